// Round 7
// baseline (117.608 us; speedup 1.0000x reference)
//
#include <hip/hip_runtime.h>
#include <hip/hip_bf16.h>
#include <cstdint>

// EdgeMLP R7: 32-edge tiles, two sub-tiles share each W1 ds_read (LDS traffic
// halved vs R6). W1 frags (32 KB) + W2 frags (4 KB) in LDS. VGPR ledger <=128
// so HW keeps 4 waves/SIMD. All-MFMA layer2 (R3-validated relabel).
// ws: [hb: nNodes*64 bf16][w1tab: 16384 bf16][w2tab: 2048 bf16]

constexpr int EMB = 64;
constexpr int HID = 128;

typedef short s16x8 __attribute__((ext_vector_type(8)));
typedef float f32x4 __attribute__((ext_vector_type(4)));

__device__ __forceinline__ unsigned short f2bf(float x) {
    unsigned u = __float_as_uint(x);
    u = (u + 0x7fffu + ((u >> 16) & 1u)) >> 16;   // RNE
    return (unsigned short)u;
}
__device__ __forceinline__ short f2bf_hw(float x) {   // hot path: HW cvt
    __hip_bfloat16 b = __float2bfloat16(x);
    return *reinterpret_cast<short*>(&b);
}

// ---- prep 1: h fp32 -> bf16 ----
__global__ void conv_h_kernel(const float* __restrict__ h,
                              unsigned short* __restrict__ hb, int n8) {
    const int i = blockIdx.x * blockDim.x + threadIdx.x;
    if (i >= n8) return;
    const float* p = h + (size_t)i * 8;
    float4 a = *reinterpret_cast<const float4*>(p);
    float4 b = *reinterpret_cast<const float4*>(p + 4);
    unsigned short r[8];
    r[0] = f2bf(a.x); r[1] = f2bf(a.y); r[2] = f2bf(a.z); r[3] = f2bf(a.w);
    r[4] = f2bf(b.x); r[5] = f2bf(b.y); r[6] = f2bf(b.z); r[7] = f2bf(b.w);
    *reinterpret_cast<uint4*>(hb + (size_t)i * 8) = *reinterpret_cast<const uint4*>(r);
}

// ---- prep 2: W1 + W2 fragment tables ----
// w1tab[i], i=((nt*4+ks)*64+lane)*8+j : bf16(W1[k][n]), k=ks*32+(lane>>4)*8+j,
//                                       n=nt*16+(lane&15)
// w2tab[q], q=(ks*64+lane)*8+j : tc=lane&15, bq=lane>>4; mt=ks*2+(j>>2), r=j&3;
//   val = (tc<2) ? bf16(W2[(mt*16+bq*4+r)*2+tc]) : 0
__global__ void pack_tabs(const float* __restrict__ W1,
                          const float* __restrict__ W2,
                          unsigned short* __restrict__ tab) {
    const int i = blockIdx.x * blockDim.x + threadIdx.x;
    if (i < 16384) {
        const int j = i & 7, lane = (i >> 3) & 63, ks = (i >> 9) & 3, nt = i >> 11;
        const int k = ks * 32 + (lane >> 4) * 8 + j;
        const int n = nt * 16 + (lane & 15);
        tab[i] = f2bf(W1[(size_t)k * HID + n]);
    } else if (i < 16384 + 2048) {
        const int q = i - 16384;
        const int j = q & 7, lane = (q >> 3) & 63, ks = q >> 9;
        const int tc = lane & 15, bq = lane >> 4;
        const int mt = ks * 2 + (j >> 2), r = j & 3;
        tab[i] = (tc < 2) ? f2bf(W2[(mt * 16 + bq * 4 + r) * 2 + tc])
                          : (unsigned short)0;
    }
}

// ---- main ----
__global__ __launch_bounds__(256, 2)
void edge_mlp_r7(const unsigned short* __restrict__ hb,
                 const unsigned short* __restrict__ tab,
                 const int* __restrict__ eidx,
                 const float* __restrict__ b1,
                 const float* __restrict__ b2,
                 float* __restrict__ out, int E, int nTiles)
{
    __shared__ uint4 w1s[2048];   // 32 KB W1 fragments
    __shared__ uint4 w2s[256];    // 4 KB  W2 fragments
    {
        const uint4* src = reinterpret_cast<const uint4*>(tab);
        #pragma unroll
        for (int r = 0; r < 8; ++r)
            w1s[r * 256 + threadIdx.x] = src[r * 256 + threadIdx.x];
        if (threadIdx.x < 256) w2s[threadIdx.x] = src[2048 + threadIdx.x];
    }
    __syncthreads();

    const int t = threadIdx.x, wid = t >> 6, lane = t & 63;
    const int tc = lane & 15, bq = lane >> 4;
    const s16x8* wf  = reinterpret_cast<const s16x8*>(w1s) + lane;  // + (nt*4+ks)*64
    const s16x8* wf2 = reinterpret_cast<const s16x8*>(w2s) + lane;  // + ks*64

    // b1 in C layout, packed bf16 (R3-validated)
    uint2 b1p[8];
    #pragma unroll
    for (int mt = 0; mt < 8; ++mt) {
        const int u0 = mt * 16 + bq * 4;
        b1p[mt].x = (unsigned)f2bf(b1[u0 + 0]) | ((unsigned)f2bf(b1[u0 + 1]) << 16);
        b1p[mt].y = (unsigned)f2bf(b1[u0 + 2]) | ((unsigned)f2bf(b1[u0 + 3]) << 16);
    }
    const float a20 = (bq == 0) ? b2[0] : 0.f;
    const float a21 = (bq == 0) ? b2[1] : 0.f;

    const int stride = gridDim.x * 4;
    int tile = blockIdx.x * 4 + wid;
    if (tile >= nTiles) return;

    int sA, dA, sB, dB;
    auto LOADIDX = [&](int tl) {
        if (tl < nTiles) {
            const int base = tl * 32;
            const int eA = min(base + tc, E - 1);
            const int eB = min(base + 16 + tc, E - 1);
            sA = eidx[eA]; dA = eidx[E + eA];
            sB = eidx[eB]; dB = eidx[E + eB];
        }
    };
    auto GATHER = [&](int s, int d, s16x8 (&xf)[4]) {
        const s16x8* ps = reinterpret_cast<const s16x8*>(hb + (size_t)s * EMB + bq * 8);
        const s16x8* pd = reinterpret_cast<const s16x8*>(hb + (size_t)d * EMB + bq * 8);
        xf[0] = ps[0]; xf[1] = ps[4];
        xf[2] = pd[0]; xf[3] = pd[4];
    };

    s16x8 xfA[4], xfB[4];
    LOADIDX(tile);
    GATHER(sA, dA, xfA);
    GATHER(sB, dB, xfB);

    while (true) {
        LOADIDX(tile + stride);   // next-tile idx prefetch (completes under layer1)

        // ---- layer 1: both sub-tiles share every W1 fragment read ----
        f32x4 accA[8], accB[8];
        #pragma unroll
        for (int mt = 0; mt < 8; ++mt) {
            f32x4 ini;
            ini[0] = __uint_as_float(b1p[mt].x << 16);
            ini[1] = __uint_as_float(b1p[mt].x & 0xffff0000u);
            ini[2] = __uint_as_float(b1p[mt].y << 16);
            ini[3] = __uint_as_float(b1p[mt].y & 0xffff0000u);
            accA[mt] = ini; accB[mt] = ini;
        }
        #pragma unroll
        for (int ks = 0; ks < 4; ++ks)
            #pragma unroll
            for (int nt = 0; nt < 8; ++nt) {
                const s16x8 w = wf[(nt * 4 + ks) * 64];
                accA[nt] = __builtin_amdgcn_mfma_f32_16x16x32_bf16(w, xfA[ks], accA[nt], 0, 0, 0);
                accB[nt] = __builtin_amdgcn_mfma_f32_16x16x32_bf16(w, xfB[ks], accB[nt], 0, 0, 0);
            }

        // ---- layer 2 (w2 frags read once, shared by both sub-tiles) ----
        {
            s16x8 w2r[4];
            #pragma unroll
            for (int ks = 0; ks < 4; ++ks) w2r[ks] = wf2[ks * 64];

            #pragma unroll
            for (int half = 0; half < 2; ++half) {
                const f32x4* acc = half ? accB : accA;
                s16x8 p[4];
                #pragma unroll
                for (int ks2 = 0; ks2 < 4; ++ks2)
                    #pragma unroll
                    for (int j = 0; j < 8; ++j) {
                        const int mt = ks2 * 2 + (j >> 2), r = j & 3;
                        p[ks2][j] = f2bf_hw(fmaxf(acc[mt][r], 0.f));
                    }
                f32x4 o = {a20, a21, 0.f, 0.f};
                #pragma unroll
                for (int ks2 = 0; ks2 < 4; ++ks2)
                    o = __builtin_amdgcn_mfma_f32_16x16x32_bf16(w2r[ks2], p[ks2], o, 0, 0, 0);
                if (lane < 16) {
                    const int eo = tile * 32 + half * 16 + lane;
                    if (eo < E)
                        *reinterpret_cast<float2*>(out + (size_t)eo * 2) =
                            make_float2(o[0], o[1]);
                }
            }
        }

        tile += stride;
        if (tile >= nTiles) break;
        GATHER(sA, dA, xfA);      // gathers for the new tile (idx already loaded)
        GATHER(sB, dB, xfB);
    }
}

// ---- fallback (ws too small; correct but slow) ----
__global__ void edge_mlp_naive(const float* __restrict__ h, const int* __restrict__ eidx,
                               const float* __restrict__ W1, const float* __restrict__ b1,
                               const float* __restrict__ W2, const float* __restrict__ b2,
                               float* __restrict__ out, int E) {
    const int e = blockIdx.x * 256 + threadIdx.x;
    if (e >= E) return;
    const float* hs = h + (size_t)eidx[e] * EMB;
    const float* hd = h + (size_t)eidx[E + e] * EMB;
    float o0 = b2[0], o1 = b2[1];
    for (int j = 0; j < HID; ++j) {
        float a = b1[j];
        for (int k = 0; k < EMB; ++k)
            a += hs[k] * W1[(size_t)k * HID + j] + hd[k] * W1[(size_t)(k + EMB) * HID + j];
        a = fmaxf(a, 0.f);
        o0 = fmaf(a, W2[j * 2 + 0], o0);
        o1 = fmaf(a, W2[j * 2 + 1], o1);
    }
    out[(size_t)e * 2 + 0] = o0;
    out[(size_t)e * 2 + 1] = o1;
}

extern "C" void kernel_launch(void* const* d_in, const int* in_sizes, int n_in,
                              void* d_out, int out_size, void* d_ws, size_t ws_size,
                              hipStream_t stream)
{
    const float* h  = (const float*)d_in[0];
    const int*   ei = (const int*)d_in[1];
    const float* W1 = (const float*)d_in[2];
    const float* b1 = (const float*)d_in[3];
    const float* W2 = (const float*)d_in[4];
    const float* b2 = (const float*)d_in[5];
    float* out = (float*)d_out;

    const int nNodes = in_sizes[0] / EMB;
    const int E      = in_sizes[1] / 2;
    const int nTiles = (E + 31) / 32;

    const size_t hbElems = (size_t)nNodes * EMB;
    const size_t need    = hbElems * 2 + (16384 + 2048) * 2;

    if (ws_size >= need) {
        unsigned short* hb  = (unsigned short*)d_ws;
        unsigned short* tab = hb + hbElems;
        const int n8 = (int)(hbElems / 8);
        hipLaunchKernelGGL(conv_h_kernel, dim3((n8 + 255) / 256), dim3(256), 0, stream,
                           h, hb, n8);
        hipLaunchKernelGGL(pack_tabs, dim3(72), dim3(256), 0, stream, W1, W2, tab);
        hipLaunchKernelGGL(edge_mlp_r7, dim3(1024), dim3(256), 0, stream,
                           hb, tab, ei, b1, b2, out, E, nTiles);
    } else {
        hipLaunchKernelGGL(edge_mlp_naive, dim3((E + 255) / 256), dim3(256), 0, stream,
                           h, ei, W1, b1, W2, b2, out, E);
    }
}

// Round 8
// 107.735 us; speedup vs baseline: 1.0916x; 1.0916x over previous
//
#include <hip/hip_runtime.h>
#include <hip/hip_bf16.h>
#include <cstdint>

// EdgeMLP R8: 32-edge tiles (two sub-tiles share every W1 ds_read), register
// ledger engineered <=128: b1 init via LDS broadcast reads (MFMA C-in), xf
// regather split around the two layer-2 halves, paired bf16 cvt in repack.
// LDS: W1 frags 32KB + W2 frags 4KB + b1 512B = 37.4KB -> 4 blocks/CU.
// ws: [hb: nNodes*64 bf16][w1tab: 16384 bf16][w2tab: 2048 bf16]

constexpr int EMB = 64;
constexpr int HID = 128;

typedef short s16x8 __attribute__((ext_vector_type(8)));
typedef float f32x4 __attribute__((ext_vector_type(4)));

__device__ __forceinline__ unsigned short f2bf(float x) {
    unsigned u = __float_as_uint(x);
    u = (u + 0x7fffu + ((u >> 16) & 1u)) >> 16;   // RNE
    return (unsigned short)u;
}

// ---- prep 1: h fp32 -> bf16 ----
__global__ void conv_h_kernel(const float* __restrict__ h,
                              unsigned short* __restrict__ hb, int n8) {
    const int i = blockIdx.x * blockDim.x + threadIdx.x;
    if (i >= n8) return;
    const float* p = h + (size_t)i * 8;
    float4 a = *reinterpret_cast<const float4*>(p);
    float4 b = *reinterpret_cast<const float4*>(p + 4);
    unsigned short r[8];
    r[0] = f2bf(a.x); r[1] = f2bf(a.y); r[2] = f2bf(a.z); r[3] = f2bf(a.w);
    r[4] = f2bf(b.x); r[5] = f2bf(b.y); r[6] = f2bf(b.z); r[7] = f2bf(b.w);
    *reinterpret_cast<uint4*>(hb + (size_t)i * 8) = *reinterpret_cast<const uint4*>(r);
}

// ---- prep 2: W1 + W2 fragment tables (R3/R6-validated layouts) ----
__global__ void pack_tabs(const float* __restrict__ W1,
                          const float* __restrict__ W2,
                          unsigned short* __restrict__ tab) {
    const int i = blockIdx.x * blockDim.x + threadIdx.x;
    if (i < 16384) {
        const int j = i & 7, lane = (i >> 3) & 63, ks = (i >> 9) & 3, nt = i >> 11;
        const int k = ks * 32 + (lane >> 4) * 8 + j;
        const int n = nt * 16 + (lane & 15);
        tab[i] = f2bf(W1[(size_t)k * HID + n]);
    } else if (i < 16384 + 2048) {
        const int q = i - 16384;
        const int j = q & 7, lane = (q >> 3) & 63, ks = q >> 9;
        const int tc = lane & 15, bq = lane >> 4;
        const int mt = ks * 2 + (j >> 2), r = j & 3;
        tab[i] = (tc < 2) ? f2bf(W2[(mt * 16 + bq * 4 + r) * 2 + tc])
                          : (unsigned short)0;
    }
}

// ---- main ----
__global__ __launch_bounds__(256, 2)
void edge_mlp_r8(const unsigned short* __restrict__ hb,
                 const unsigned short* __restrict__ tab,
                 const int* __restrict__ eidx,
                 const float* __restrict__ b1,
                 const float* __restrict__ b2,
                 float* __restrict__ out, int E, int nTiles)
{
    __shared__ uint4 w1s[2048];   // 32 KB W1 fragments
    __shared__ uint4 w2s[256];    // 4 KB  W2 fragments
    __shared__ float b1s[128];    // 512 B b1 (linear == C-layout table)
    {
        const uint4* src = reinterpret_cast<const uint4*>(tab);
        #pragma unroll
        for (int r = 0; r < 8; ++r)
            w1s[r * 256 + threadIdx.x] = src[r * 256 + threadIdx.x];
        w2s[threadIdx.x] = src[2048 + threadIdx.x];
        if (threadIdx.x < 128) b1s[threadIdx.x] = b1[threadIdx.x];
    }
    __syncthreads();

    const int t = threadIdx.x, wid = t >> 6, lane = t & 63;
    const int tc = lane & 15, bq = lane >> 4;
    const s16x8* wf  = reinterpret_cast<const s16x8*>(w1s) + lane;  // + (nt*4+ks)*64
    const s16x8* wf2 = reinterpret_cast<const s16x8*>(w2s) + lane;  // + ks*64
    const float* b1v = b1s + bq * 4;                                // + nt*16

    const float a20 = (bq == 0) ? b2[0] : 0.f;
    const float a21 = (bq == 0) ? b2[1] : 0.f;

    const int stride = gridDim.x * 4;
    int tile = blockIdx.x * 4 + wid;
    if (tile >= nTiles) return;

    int sA, dA, sB, dB;
    auto LOADIDX = [&](int tl) {
        if (tl < nTiles) {
            const int base = tl * 32;
            const int eA = min(base + tc, E - 1);
            const int eB = min(base + 16 + tc, E - 1);
            sA = eidx[eA]; dA = eidx[E + eA];
            sB = eidx[eB]; dB = eidx[E + eB];
        }
    };
    auto GATHER = [&](int s, int d, s16x8 (&xf)[4]) {
        const s16x8* ps = reinterpret_cast<const s16x8*>(hb + (size_t)s * EMB + bq * 8);
        const s16x8* pd = reinterpret_cast<const s16x8*>(hb + (size_t)d * EMB + bq * 8);
        xf[0] = ps[0]; xf[1] = ps[4];
        xf[2] = pd[0]; xf[3] = pd[4];
    };

    s16x8 xfA[4], xfB[4];
    LOADIDX(tile);
    GATHER(sA, dA, xfA);
    GATHER(sB, dB, xfB);

    while (true) {
        LOADIDX(tile + stride);   // next-tile idx: in flight during whole body

        // ---- layer 1: ks=0 takes C-in straight from the LDS b1 table ----
        f32x4 accA[8], accB[8];
        #pragma unroll
        for (int nt = 0; nt < 8; ++nt) {
            const f32x4 ini = *reinterpret_cast<const f32x4*>(b1v + nt * 16);
            const s16x8 w = wf[(nt * 4) * 64];
            accA[nt] = __builtin_amdgcn_mfma_f32_16x16x32_bf16(w, xfA[0], ini, 0, 0, 0);
            accB[nt] = __builtin_amdgcn_mfma_f32_16x16x32_bf16(w, xfB[0], ini, 0, 0, 0);
        }
        #pragma unroll
        for (int ks = 1; ks < 4; ++ks)
            #pragma unroll
            for (int nt = 0; nt < 8; ++nt) {
                const s16x8 w = wf[(nt * 4 + ks) * 64];
                accA[nt] = __builtin_amdgcn_mfma_f32_16x16x32_bf16(w, xfA[ks], accA[nt], 0, 0, 0);
                accB[nt] = __builtin_amdgcn_mfma_f32_16x16x32_bf16(w, xfB[ks], accB[nt], 0, 0, 0);
            }

        const bool last = (tile + stride >= nTiles);

        // ---- layer 2 ----
        s16x8 w2r[4];
        #pragma unroll
        for (int ks = 0; ks < 4; ++ks) w2r[ks] = wf2[ks * 64];

        // half A
        {
            f32x4 o = {a20, a21, 0.f, 0.f};
            #pragma unroll
            for (int ks2 = 0; ks2 < 4; ++ks2) {
                s16x8 p;
                #pragma unroll
                for (int jj = 0; jj < 4; ++jj) {
                    const int mt = ks2 * 2 + (jj >> 1), r = (jj & 1) * 2;
                    float2 v = make_float2(fmaxf(accA[mt][r], 0.f),
                                           fmaxf(accA[mt][r + 1], 0.f));
                    __hip_bfloat162 bb = __float22bfloat162_rn(v);
                    reinterpret_cast<unsigned*>(&p)[jj] = *reinterpret_cast<unsigned*>(&bb);
                }
                o = __builtin_amdgcn_mfma_f32_16x16x32_bf16(w2r[ks2], p, o, 0, 0, 0);
            }
            if (lane < 16) {
                const int eo = tile * 32 + lane;
                if (eo < E)
                    *reinterpret_cast<float2*>(out + (size_t)eo * 2) = make_float2(o[0], o[1]);
            }
        }

        if (!last) GATHER(sA, dA, xfA);   // accA dead: refill under half B

        // half B
        {
            f32x4 o = {a20, a21, 0.f, 0.f};
            #pragma unroll
            for (int ks2 = 0; ks2 < 4; ++ks2) {
                s16x8 p;
                #pragma unroll
                for (int jj = 0; jj < 4; ++jj) {
                    const int mt = ks2 * 2 + (jj >> 1), r = (jj & 1) * 2;
                    float2 v = make_float2(fmaxf(accB[mt][r], 0.f),
                                           fmaxf(accB[mt][r + 1], 0.f));
                    __hip_bfloat162 bb = __float22bfloat162_rn(v);
                    reinterpret_cast<unsigned*>(&p)[jj] = *reinterpret_cast<unsigned*>(&bb);
                }
                o = __builtin_amdgcn_mfma_f32_16x16x32_bf16(w2r[ks2], p, o, 0, 0, 0);
            }
            if (lane < 16) {
                const int eo = tile * 32 + 16 + lane;
                if (eo < E)
                    *reinterpret_cast<float2*>(out + (size_t)eo * 2) = make_float2(o[0], o[1]);
            }
        }

        if (last) break;
        GATHER(sB, dB, xfB);
        tile += stride;
    }
}

// ---- fallback (ws too small; correct but slow) ----
__global__ void edge_mlp_naive(const float* __restrict__ h, const int* __restrict__ eidx,
                               const float* __restrict__ W1, const float* __restrict__ b1,
                               const float* __restrict__ W2, const float* __restrict__ b2,
                               float* __restrict__ out, int E) {
    const int e = blockIdx.x * 256 + threadIdx.x;
    if (e >= E) return;
    const float* hs = h + (size_t)eidx[e] * EMB;
    const float* hd = h + (size_t)eidx[E + e] * EMB;
    float o0 = b2[0], o1 = b2[1];
    for (int j = 0; j < HID; ++j) {
        float a = b1[j];
        for (int k = 0; k < EMB; ++k)
            a += hs[k] * W1[(size_t)k * HID + j] + hd[k] * W1[(size_t)(k + EMB) * HID + j];
        a = fmaxf(a, 0.f);
        o0 = fmaf(a, W2[j * 2 + 0], o0);
        o1 = fmaf(a, W2[j * 2 + 1], o1);
    }
    out[(size_t)e * 2 + 0] = o0;
    out[(size_t)e * 2 + 1] = o1;
}

extern "C" void kernel_launch(void* const* d_in, const int* in_sizes, int n_in,
                              void* d_out, int out_size, void* d_ws, size_t ws_size,
                              hipStream_t stream)
{
    const float* h  = (const float*)d_in[0];
    const int*   ei = (const int*)d_in[1];
    const float* W1 = (const float*)d_in[2];
    const float* b1 = (const float*)d_in[3];
    const float* W2 = (const float*)d_in[4];
    const float* b2 = (const float*)d_in[5];
    float* out = (float*)d_out;

    const int nNodes = in_sizes[0] / EMB;
    const int E      = in_sizes[1] / 2;
    const int nTiles = (E + 31) / 32;

    const size_t hbElems = (size_t)nNodes * EMB;
    const size_t need    = hbElems * 2 + (16384 + 2048) * 2;

    if (ws_size >= need) {
        unsigned short* hb  = (unsigned short*)d_ws;
        unsigned short* tab = hb + hbElems;
        const int n8 = (int)(hbElems / 8);
        hipLaunchKernelGGL(conv_h_kernel, dim3((n8 + 255) / 256), dim3(256), 0, stream,
                           h, hb, n8);
        hipLaunchKernelGGL(pack_tabs, dim3(72), dim3(256), 0, stream, W1, W2, tab);
        hipLaunchKernelGGL(edge_mlp_r8, dim3(1024), dim3(256), 0, stream,
                           hb, tab, ei, b1, b2, out, E, nTiles);
    } else {
        hipLaunchKernelGGL(edge_mlp_naive, dim3((E + 255) / 256), dim3(256), 0, stream,
                           h, ei, W1, b1, W2, b2, out, E);
    }
}

// Round 9
// 87.090 us; speedup vs baseline: 1.3504x; 1.2371x over previous
//
#include <hip/hip_runtime.h>
#include <hip/hip_bf16.h>
#include <cstdint>

// EdgeMLP R9 = R6 (16-edge tile, no-spill, 96us) + R8's validated VALU cuts:
//   - b1 lives in LDS as f32, used directly as MFMA C-in (no unpack, -16 VGPR)
//   - repack via paired v_cvt_pk_bf16_f32
//   - W2 frags persistent in 16 regs, loaded once from packed table
// Ledger ~95 VGPR -> no spill at the 128 allocator ceiling.
// ws: [hb: nNodes*64 bf16][w1tab: 16384 bf16][w2tab: 2048 bf16]

constexpr int EMB = 64;
constexpr int HID = 128;

typedef short s16x8 __attribute__((ext_vector_type(8)));
typedef float f32x4 __attribute__((ext_vector_type(4)));

__device__ __forceinline__ unsigned short f2bf(float x) {
    unsigned u = __float_as_uint(x);
    u = (u + 0x7fffu + ((u >> 16) & 1u)) >> 16;   // RNE
    return (unsigned short)u;
}

// ---- prep 1: h fp32 -> bf16 ----
__global__ void conv_h_kernel(const float* __restrict__ h,
                              unsigned short* __restrict__ hb, int n8) {
    const int i = blockIdx.x * blockDim.x + threadIdx.x;
    if (i >= n8) return;
    const float* p = h + (size_t)i * 8;
    float4 a = *reinterpret_cast<const float4*>(p);
    float4 b = *reinterpret_cast<const float4*>(p + 4);
    unsigned short r[8];
    r[0] = f2bf(a.x); r[1] = f2bf(a.y); r[2] = f2bf(a.z); r[3] = f2bf(a.w);
    r[4] = f2bf(b.x); r[5] = f2bf(b.y); r[6] = f2bf(b.z); r[7] = f2bf(b.w);
    *reinterpret_cast<uint4*>(hb + (size_t)i * 8) = *reinterpret_cast<const uint4*>(r);
}

// ---- prep 2: W1 + W2 fragment tables (validated layouts) ----
// w1tab[i], i=((nt*4+ks)*64+lane)*8+j : bf16(W1[k][n]), k=ks*32+(lane>>4)*8+j,
//                                       n=nt*16+(lane&15)
// w2tab[q], q=(ks*64+lane)*8+j : tc=lane&15, bq=lane>>4; mt=ks*2+(j>>2), r=j&3;
//   val = (tc<2) ? bf16(W2[(mt*16+bq*4+r)*2+tc]) : 0
__global__ void pack_tabs(const float* __restrict__ W1,
                          const float* __restrict__ W2,
                          unsigned short* __restrict__ tab) {
    const int i = blockIdx.x * blockDim.x + threadIdx.x;
    if (i < 16384) {
        const int j = i & 7, lane = (i >> 3) & 63, ks = (i >> 9) & 3, nt = i >> 11;
        const int k = ks * 32 + (lane >> 4) * 8 + j;
        const int n = nt * 16 + (lane & 15);
        tab[i] = f2bf(W1[(size_t)k * HID + n]);
    } else if (i < 16384 + 2048) {
        const int q = i - 16384;
        const int j = q & 7, lane = (q >> 3) & 63, ks = q >> 9;
        const int tc = lane & 15, bq = lane >> 4;
        const int mt = ks * 2 + (j >> 2), r = j & 3;
        tab[i] = (tc < 2) ? f2bf(W2[(mt * 16 + bq * 4 + r) * 2 + tc])
                          : (unsigned short)0;
    }
}

// ---- main ----
__global__ __launch_bounds__(256, 2)
void edge_mlp_r9(const unsigned short* __restrict__ hb,
                 const unsigned short* __restrict__ tab,
                 const int* __restrict__ eidx,
                 const float* __restrict__ b1,
                 const float* __restrict__ b2,
                 float* __restrict__ out, int E, int nTiles)
{
    __shared__ uint4 w1s[2048];   // 32 KB W1 fragments
    __shared__ float b1s[128];    // 512 B b1 (linear == C-layout table)
    {
        const uint4* src = reinterpret_cast<const uint4*>(tab);
        #pragma unroll
        for (int r = 0; r < 8; ++r)
            w1s[r * 256 + threadIdx.x] = src[r * 256 + threadIdx.x];
        if (threadIdx.x < 128) b1s[threadIdx.x] = b1[threadIdx.x];
    }
    __syncthreads();

    const int t = threadIdx.x, wid = t >> 6, lane = t & 63;
    const int tc = lane & 15, bq = lane >> 4;
    const s16x8* wf = reinterpret_cast<const s16x8*>(w1s) + lane;  // + (nt*4+ks)*64
    const float* b1v = b1s + bq * 4;                               // + nt*16

    // W2 fragments persistent in registers (16), loaded once from packed table
    s16x8 w2f[4];
    #pragma unroll
    for (int ks = 0; ks < 4; ++ks)
        w2f[ks] = *reinterpret_cast<const s16x8*>(tab + 16384 + ((ks * 64 + lane) * 8));

    const float a20 = (bq == 0) ? b2[0] : 0.f;
    const float a21 = (bq == 0) ? b2[1] : 0.f;

    const int stride = gridDim.x * 4;
    int tile = blockIdx.x * 4 + wid;
    if (tile >= nTiles) return;

    auto LOADIDX = [&](int tl, int& s, int& d) {
        if (tl < nTiles) {
            const int e = min(tl * 16 + tc, E - 1);
            s = eidx[e]; d = eidx[E + e];
        } else { s = 0; d = 0; }
    };
    auto GATHER = [&](int s, int d, s16x8 (&xf)[4]) {
        const s16x8* ps = reinterpret_cast<const s16x8*>(hb + (size_t)s * EMB + bq * 8);
        const s16x8* pd = reinterpret_cast<const s16x8*>(hb + (size_t)d * EMB + bq * 8);
        xf[0] = ps[0]; xf[1] = ps[4];
        xf[2] = pd[0]; xf[3] = pd[4];
    };
    auto COMPUTE = [&](int tl, s16x8 (&xf)[4]) {
        f32x4 acc[8];
        // ks = 0: C-in comes straight from the LDS b1 table (broadcast reads)
        #pragma unroll
        for (int nt = 0; nt < 8; ++nt) {
            const f32x4 ini = *reinterpret_cast<const f32x4*>(b1v + nt * 16);
            acc[nt] = __builtin_amdgcn_mfma_f32_16x16x32_bf16(
                          wf[(nt * 4) * 64], xf[0], ini, 0, 0, 0);
        }
        #pragma unroll
        for (int ks = 1; ks < 4; ++ks)
            #pragma unroll
            for (int nt = 0; nt < 8; ++nt)
                acc[nt] = __builtin_amdgcn_mfma_f32_16x16x32_bf16(
                              wf[(nt * 4 + ks) * 64], xf[ks], acc[nt], 0, 0, 0);

        // relu + paired bf16 cvt repack -> layer-2 B-frag; 4 more MFMAs
        f32x4 o = {a20, a21, 0.f, 0.f};
        #pragma unroll
        for (int ks2 = 0; ks2 < 4; ++ks2) {
            s16x8 p;
            #pragma unroll
            for (int jj = 0; jj < 4; ++jj) {
                const int mt = ks2 * 2 + (jj >> 1), r = (jj & 1) * 2;
                float2 v = make_float2(fmaxf(acc[mt][r], 0.f),
                                       fmaxf(acc[mt][r + 1], 0.f));
                __hip_bfloat162 bb = __float22bfloat162_rn(v);
                reinterpret_cast<unsigned*>(&p)[jj] = *reinterpret_cast<unsigned*>(&bb);
            }
            o = __builtin_amdgcn_mfma_f32_16x16x32_bf16(w2f[ks2], p, o, 0, 0, 0);
        }

        if (lane < 16) {
            const int eo = tl * 16 + lane;
            if (eo < E)
                *reinterpret_cast<float2*>(out + (size_t)eo * 2) = make_float2(o[0], o[1]);
        }
    };

    // ---- depth-2 pipeline (R6-validated) ----
    int sN, dN;
    LOADIDX(tile, sN, dN);
    s16x8 xC[4], xN[4];
    GATHER(sN, dN, xC);
    LOADIDX(tile + stride, sN, dN);

    while (true) {
        GATHER(sN, dN, xN);
        LOADIDX(tile + 2 * stride, sN, dN);
        COMPUTE(tile, xC);
        tile += stride;
        if (tile >= nTiles) break;

        GATHER(sN, dN, xC);
        LOADIDX(tile + 2 * stride, sN, dN);
        COMPUTE(tile, xN);
        tile += stride;
        if (tile >= nTiles) break;
    }
}

// ---- fallback (ws too small; correct but slow) ----
__global__ void edge_mlp_naive(const float* __restrict__ h, const int* __restrict__ eidx,
                               const float* __restrict__ W1, const float* __restrict__ b1,
                               const float* __restrict__ W2, const float* __restrict__ b2,
                               float* __restrict__ out, int E) {
    const int e = blockIdx.x * 256 + threadIdx.x;
    if (e >= E) return;
    const float* hs = h + (size_t)eidx[e] * EMB;
    const float* hd = h + (size_t)eidx[E + e] * EMB;
    float o0 = b2[0], o1 = b2[1];
    for (int j = 0; j < HID; ++j) {
        float a = b1[j];
        for (int k = 0; k < EMB; ++k)
            a += hs[k] * W1[(size_t)k * HID + j] + hd[k] * W1[(size_t)(k + EMB) * HID + j];
        a = fmaxf(a, 0.f);
        o0 = fmaf(a, W2[j * 2 + 0], o0);
        o1 = fmaf(a, W2[j * 2 + 1], o1);
    }
    out[(size_t)e * 2 + 0] = o0;
    out[(size_t)e * 2 + 1] = o1;
}

extern "C" void kernel_launch(void* const* d_in, const int* in_sizes, int n_in,
                              void* d_out, int out_size, void* d_ws, size_t ws_size,
                              hipStream_t stream)
{
    const float* h  = (const float*)d_in[0];
    const int*   ei = (const int*)d_in[1];
    const float* W1 = (const float*)d_in[2];
    const float* b1 = (const float*)d_in[3];
    const float* W2 = (const float*)d_in[4];
    const float* b2 = (const float*)d_in[5];
    float* out = (float*)d_out;

    const int nNodes = in_sizes[0] / EMB;
    const int E      = in_sizes[1] / 2;
    const int nTiles = (E + 15) / 16;

    const size_t hbElems = (size_t)nNodes * EMB;
    const size_t need    = hbElems * 2 + (16384 + 2048) * 2;

    if (ws_size >= need) {
        unsigned short* hb  = (unsigned short*)d_ws;
        unsigned short* tab = hb + hbElems;
        const int n8 = (int)(hbElems / 8);
        hipLaunchKernelGGL(conv_h_kernel, dim3((n8 + 255) / 256), dim3(256), 0, stream,
                           h, hb, n8);
        hipLaunchKernelGGL(pack_tabs, dim3(72), dim3(256), 0, stream, W1, W2, tab);
        hipLaunchKernelGGL(edge_mlp_r9, dim3(1024), dim3(256), 0, stream,
                           hb, tab, ei, b1, b2, out, E, nTiles);
    } else {
        hipLaunchKernelGGL(edge_mlp_naive, dim3((E + 255) / 256), dim3(256), 0, stream,
                           h, ei, W1, b1, W2, b2, out, E);
    }
}